// Round 1
// baseline (4046.063 us; speedup 1.0000x reference)
//
#include <hip/hip_runtime.h>

// Shapes: B=16, H=W=128. x0: 145ch (64 f1 + 81 cv), x1: 128, x2: 64, x3: 32, out: 2.

__device__ __forceinline__ unsigned short f2bf_bits(float f) {
  unsigned int u = __float_as_uint(f);
  unsigned int r = (u + 0x7FFFu + ((u >> 16) & 1u)) >> 16;  // RNE
  return (unsigned short)r;
}
__device__ __forceinline__ float bf_bits2f(unsigned short v) {
  return __uint_as_float(((unsigned int)v) << 16);
}

// ---------------- pack f1 (fp32 -> bf16 into x0 channels 0..63) ----------------
__global__ void pack_f1_kernel(const float4* __restrict__ f1, ushort* __restrict__ x0) {
  int i4 = blockIdx.x * blockDim.x + threadIdx.x;  // 0 .. 16*64*128*128/4 - 1
  float4 v = f1[i4];
  int i = i4 << 2;
  int b = i >> 20;                  // / (64*16384)
  int rem = i & ((1 << 20) - 1);
  int dest = b * (145 << 14) + rem; // element offset into x0
  ushort4 u;
  u.x = f2bf_bits(v.x);
  u.y = f2bf_bits(v.y);
  u.z = f2bf_bits(v.z);
  u.w = f2bf_bits(v.w);
  reinterpret_cast<ushort4*>(x0)[dest >> 2] = u;
}

// ---------------- cost volume -> x0 channels 64..144 ----------------
// cv[(i+4)*9+(j+4)][h][w] = (1/64) sum_c f1[c,h,w] * f2[c,h-i,w-j] (0 outside)
__global__ void cost_volume_kernel(const float* __restrict__ f1,
                                   const float* __restrict__ f2,
                                   ushort* __restrict__ x0) {
  const int h = blockIdx.x;
  const int b = blockIdx.y;
  const int w = threadIdx.x;  // 0..127

  __shared__ float sf2[8][9][136];  // tile col t <-> f2 w = t-4 ; row a <-> f2 h = h+a-4
  __shared__ float sf1[8][128];

  float acc[81];
#pragma unroll
  for (int k = 0; k < 81; ++k) acc[k] = 0.f;

  for (int c0 = 0; c0 < 64; c0 += 8) {
    __syncthreads();
    for (int e = threadIdx.x; e < 8 * 128; e += 128) {
      int ci = e >> 7, ww = e & 127;
      sf1[ci][ww] = f1[((b * 64 + c0 + ci) * 128 + h) * 128 + ww];
    }
    for (int e = threadIdx.x; e < 8 * 9 * 136; e += 128) {
      int ci = e / 1224;
      int rem = e - ci * 1224;
      int a = rem / 136;
      int t = rem - a * 136;
      int hh = h + a - 4;
      int ww = t - 4;
      float v = 0.f;
      if ((unsigned)hh < 128u && (unsigned)ww < 128u)
        v = f2[((b * 64 + c0 + ci) * 128 + hh) * 128 + ww];
      sf2[ci][a][t] = v;
    }
    __syncthreads();

    for (int ci = 0; ci < 8; ++ci) {
      float f1v = sf1[ci][w];
#pragma unroll
      for (int ii = 0; ii < 9; ++ii) {  // ii = i+4 ; needed f2 row = h+4-i -> tile row 8-ii
        float f2v[9];
#pragma unroll
        for (int t = 0; t < 9; ++t) f2v[t] = sf2[ci][8 - ii][w + t];
#pragma unroll
        for (int jj = 0; jj < 9; ++jj)  // jj = j+4 ; tile col = w+8-jj
          acc[ii * 9 + jj] += f1v * f2v[8 - jj];
      }
    }
  }

  const float inv = 1.0f / 64.0f;
#pragma unroll
  for (int idx = 0; idx < 81; ++idx) {
    x0[((b * 145 + 64 + idx) << 14) + (h << 7) + w] = f2bf_bits(acc[idx] * inv);
  }
}

// ---------------- direct 3x3 SAME conv (correlation), bf16 in, fp32 accum ----------------
// Block: COUT_CHUNK co x 8 h x 128 w. 256 threads: thread = (hg, w), 4 rows x COUT_CHUNK accs.
template <int CIN, int COUT_CHUNK, bool RELU, typename OutT>
__global__ __launch_bounds__(256, 2) void conv3x3_kernel(
    const ushort* __restrict__ xin, const float* __restrict__ wgt,
    const float* __restrict__ bias, OutT* __restrict__ out, const int cout_total) {
  constexpr int CHUNKS = (CIN + 7) / 8;
  __shared__ float xt[8][10][132];           // row 0 <-> h0-1 ; col 0 <-> w=-1
  __shared__ float wt[COUT_CHUNK][8][9];

  const int co0 = blockIdx.x * COUT_CHUNK;
  const int h0 = blockIdx.y * 8;
  const int b = blockIdx.z;
  const int tid = threadIdx.x;
  const int w = tid & 127;
  const int hg = tid >> 7;  // 0..1

  float acc[4][COUT_CHUNK];
#pragma unroll
  for (int k = 0; k < 4; ++k)
#pragma unroll
    for (int c = 0; c < COUT_CHUNK; ++c) acc[k][c] = 0.f;

  for (int ch = 0; ch < CHUNKS; ++ch) {
    const int c0 = ch * 8;
    __syncthreads();
    // stage input tile (zero pad OOB and tail channels)
    for (int e = tid; e < 8 * 10 * 130; e += 256) {
      int ci = e / 1300;
      int rem = e - ci * 1300;
      int hh = rem / 130;
      int ww = rem - hh * 130;
      int gh = h0 + hh - 1, gw = ww - 1;
      float v = 0.f;
      if ((c0 + ci) < CIN && (unsigned)gh < 128u && (unsigned)gw < 128u)
        v = bf_bits2f(xin[((b * CIN + c0 + ci) << 14) + (gh << 7) + gw]);
      xt[ci][hh][ww] = v;
    }
    // stage weights
    for (int e = tid; e < COUT_CHUNK * 8 * 9; e += 256) {
      int co = e / 72;
      int rem = e - co * 72;
      int ci = rem / 9;
      int rs = rem - ci * 9;
      float v = 0.f;
      if ((c0 + ci) < CIN) v = wgt[((co0 + co) * CIN + c0 + ci) * 9 + rs];
      wt[co][ci][rs] = v;
    }
    __syncthreads();

    for (int ci = 0; ci < 8; ++ci) {
#pragma unroll
      for (int r = 0; r < 3; ++r) {
#pragma unroll
        for (int s = 0; s < 3; ++s) {
          float xv[4];
#pragma unroll
          for (int k = 0; k < 4; ++k) xv[k] = xt[ci][hg * 4 + k + r][w + s];
#pragma unroll
          for (int c = 0; c < COUT_CHUNK; ++c) {
            float wv = wt[c][ci][r * 3 + s];
#pragma unroll
            for (int k = 0; k < 4; ++k) acc[k][c] += xv[k] * wv;
          }
        }
      }
    }
  }

#pragma unroll
  for (int c = 0; c < COUT_CHUNK; ++c) {
    float bs = bias[co0 + c];
#pragma unroll
    for (int k = 0; k < 4; ++k) {
      float v = acc[k][c] + bs;
      if (RELU) v = fmaxf(v, 0.f);
      int h = h0 + hg * 4 + k;
      long idx = ((long)(b * cout_total + co0 + c) << 14) + (h << 7) + w;
      if constexpr (__is_same(OutT, float)) {
        out[idx] = v;
      } else {
        out[idx] = f2bf_bits(v);
      }
    }
  }
}

extern "C" void kernel_launch(void* const* d_in, const int* in_sizes, int n_in,
                              void* d_out, int out_size, void* d_ws, size_t ws_size,
                              hipStream_t stream) {
  (void)in_sizes; (void)n_in; (void)out_size; (void)ws_size;
  const float* f1 = (const float*)d_in[0];
  const float* f2 = (const float*)d_in[1];
  const float* w1 = (const float*)d_in[2];
  const float* b1 = (const float*)d_in[3];
  const float* w2 = (const float*)d_in[4];
  const float* b2 = (const float*)d_in[5];
  const float* w3 = (const float*)d_in[6];
  const float* b3 = (const float*)d_in[7];
  const float* w4 = (const float*)d_in[8];
  const float* b4 = (const float*)d_in[9];
  float* out = (float*)d_out;

  char* ws = (char*)d_ws;
  size_t off = 0;
  ushort* x0 = (ushort*)(ws + off); off += (size_t)16 * 145 * 128 * 128 * 2;
  ushort* x1 = (ushort*)(ws + off); off += (size_t)16 * 128 * 128 * 128 * 2;
  ushort* x2 = (ushort*)(ws + off); off += (size_t)16 * 64 * 128 * 128 * 2;
  ushort* x3 = (ushort*)(ws + off);

  // x0 ch 0..63 = bf16(f1)
  pack_f1_kernel<<<16384, 256, 0, stream>>>((const float4*)f1, x0);
  // x0 ch 64..144 = cost volume
  cost_volume_kernel<<<dim3(128, 16), 128, 0, stream>>>(f1, f2, x0);
  // convs
  conv3x3_kernel<145, 16, true, ushort><<<dim3(8, 16, 16), 256, 0, stream>>>(x0, w1, b1, x1, 128);
  conv3x3_kernel<128, 16, true, ushort><<<dim3(4, 16, 16), 256, 0, stream>>>(x1, w2, b2, x2, 64);
  conv3x3_kernel<64, 16, true, ushort><<<dim3(2, 16, 16), 256, 0, stream>>>(x2, w3, b3, x3, 32);
  conv3x3_kernel<32, 2, false, float><<<dim3(1, 16, 16), 256, 0, stream>>>(x3, w4, b4, out, 2);
}

// Round 2
// 1434.907 us; speedup vs baseline: 2.8197x; 2.8197x over previous
//
#include <hip/hip_runtime.h>

// B=16, H=W=128. NHWC bf16 activations: x0 160ch (64 f1 + 81 cv + 15 zero),
// x1 128ch, x2 64ch, x3 32ch. Output [B,2,H,W] fp32 planar.

typedef __bf16 bf16x8 __attribute__((ext_vector_type(8)));
typedef float f32x4 __attribute__((ext_vector_type(4)));

__device__ __forceinline__ unsigned short f2bf_bits(float f) {
  unsigned int u = __float_as_uint(f);
  unsigned int r = (u + 0x7FFFu + ((u >> 16) & 1u)) >> 16;  // RNE
  return (unsigned short)r;
}

// ---------------- weight prepack: OIHW fp32 -> B-fragment lane order bf16 ----
// wp[(c*9+rs)*NFRAG + nf][lane] = uint4 of 8 bf16: W[co=nf*16+(lane&15)][ci=c*32+8*(lane>>4)+e][rs]
__global__ void prep_w_kernel(const float* __restrict__ w, uint4* __restrict__ wp,
                              int CIN, int COUT, int CHUNKS, int NFRAG) {
  int idx = blockIdx.x * 256 + threadIdx.x;
  int total = CHUNKS * 9 * NFRAG * 64;
  if (idx >= total) return;
  int lane = idx & 63;
  int fi = idx >> 6;
  int nf = fi % NFRAG;
  int t = fi / NFRAG;
  int rs = t % 9;
  int c = t / 9;
  int co = nf * 16 + (lane & 15);
  int cib = c * 32 + (lane >> 4) * 8;
  union { uint4 q; ushort s[8]; } pk;
#pragma unroll
  for (int e = 0; e < 8; ++e) {
    int ci = cib + e;
    float v = (ci < CIN && co < COUT) ? w[(co * CIN + ci) * 9 + rs] : 0.f;
    pk.s[e] = f2bf_bits(v);
  }
  wp[idx] = pk.q;
}

// ---------------- cost volume + f1 pack -> x0 NHWC (160 ch) ----------------
__global__ void cost_volume_kernel(const float* __restrict__ f1,
                                   const float* __restrict__ f2,
                                   ushort* __restrict__ x0) {
  const int h = blockIdx.x;
  const int b = blockIdx.y;
  const int w = threadIdx.x;  // 0..127

  __shared__ float sf2[8][9][136];  // col t <-> f2 w = t-4 ; row a <-> f2 h = h+a-4
  __shared__ float sf1[8][128];

  float acc[81];
#pragma unroll
  for (int k = 0; k < 81; ++k) acc[k] = 0.f;

  const long pixbase = ((long)(b * 128 + h) * 128 + w) * 160;

  for (int c0 = 0; c0 < 64; c0 += 8) {
    __syncthreads();
    for (int e = threadIdx.x; e < 8 * 128; e += 128) {
      int ci = e >> 7, ww = e & 127;
      sf1[ci][ww] = f1[((b * 64 + c0 + ci) * 128 + h) * 128 + ww];
    }
    for (int e = threadIdx.x; e < 8 * 9 * 136; e += 128) {
      int ci = e / 1224;
      int rem = e - ci * 1224;
      int a = rem / 136;
      int t = rem - a * 136;
      int hh = h + a - 4;
      int ww = t - 4;
      float v = 0.f;
      if ((unsigned)hh < 128u && (unsigned)ww < 128u)
        v = f2[((b * 64 + c0 + ci) * 128 + hh) * 128 + ww];
      sf2[ci][a][t] = v;
    }
    __syncthreads();

    // pack this f1 chunk into x0 channels c0..c0+7 (NHWC)
    {
      union { uint4 q; ushort s[8]; } pk;
#pragma unroll
      for (int e = 0; e < 8; ++e) pk.s[e] = f2bf_bits(sf1[e][w]);
      *reinterpret_cast<uint4*>(&x0[pixbase + c0]) = pk.q;
    }

    for (int ci = 0; ci < 8; ++ci) {
      float f1v = sf1[ci][w];
#pragma unroll
      for (int ii = 0; ii < 9; ++ii) {
        float f2v[9];
#pragma unroll
        for (int t = 0; t < 9; ++t) f2v[t] = sf2[ci][8 - ii][w + t];
#pragma unroll
        for (int jj = 0; jj < 9; ++jj)
          acc[ii * 9 + jj] += f1v * f2v[8 - jj];
      }
    }
  }

  // write cv (ch 64..144) + zero pad (ch 145..159)
  const float inv = 1.0f / 64.0f;
#pragma unroll
  for (int t = 0; t < 12; ++t) {
    union { uint4 q; ushort s[8]; } ob;
#pragma unroll
    for (int e = 0; e < 8; ++e) {
      int idx = t * 8 + e;
      ob.s[e] = (idx < 81) ? f2bf_bits(acc[idx] * inv) : (ushort)0;
    }
    *reinterpret_cast<uint4*>(&x0[pixbase + 64 + t * 8]) = ob.q;
  }
}

// ---------------- implicit-GEMM 3x3 conv via bf16 MFMA ----------------
// Block: 256 thr = 4 waves; tile M=128 (one output row), N=COUT.
// Wave wid: pixels m0=wid*32..+31 (2 M-frags), all N-frags.
// K loop: ci chunks of 32 (LDS-staged [3 rows][130 w][32 ci] swizzled) x 9 shifts.
template <int CPAD, int COUT, bool RELU, bool PLANAR>
__global__ __launch_bounds__(256)
void conv_mfma_kernel(const ushort* __restrict__ xin, const uint4* __restrict__ wp,
                      const float* __restrict__ bias, void* __restrict__ outv) {
  constexpr int CHUNKS = CPAD / 32;
  constexpr int NFRAG = COUT / 16;

  __shared__ ushort sX[3 * 130 * 32];  // 24960 B; 16B group at ((row*130+wl)*4 + (g^sw(wl)))*8

  const int bid = blockIdx.x;    // = b*128 + h
  const int h = bid & 127;
  const int b = bid >> 7;
  const int tid = threadIdx.x;
  const int lane = tid & 63;
  const int wid = tid >> 6;
  const int m0 = wid * 32;
  const int l15 = lane & 15;
  const int lg = lane >> 4;

  f32x4 acc[2][NFRAG];
#pragma unroll
  for (int mf = 0; mf < 2; ++mf)
#pragma unroll
    for (int nf = 0; nf < NFRAG; ++nf) acc[mf][nf] = {0.f, 0.f, 0.f, 0.f};

  for (int c = 0; c < CHUNKS; ++c) {
    const int c0 = c * 32;
    __syncthreads();
    for (int e = tid; e < 3 * 130 * 4; e += 256) {
      int row = e / 520;
      int rem = e - row * 520;
      int wl = rem >> 2;
      int g = rem & 3;
      int gh = h + row - 1;
      int gw = wl - 1;
      uint4 v = make_uint4(0u, 0u, 0u, 0u);
      if ((unsigned)gh < 128u && (unsigned)gw < 128u)
        v = *reinterpret_cast<const uint4*>(
            &xin[((long)(b * 128 + gh) * 128 + gw) * CPAD + c0 + g * 8]);
      int sw = (wl + (wl >> 2)) & 3;
      *reinterpret_cast<uint4*>(&sX[((row * 130 + wl) * 4 + (g ^ sw)) * 8]) = v;
    }
    __syncthreads();

#pragma unroll
    for (int rs = 0; rs < 9; ++rs) {
      const int r = rs / 3, s = rs % 3;
      bf16x8 afr[2];
#pragma unroll
      for (int mf = 0; mf < 2; ++mf) {
        int wl = m0 + mf * 16 + l15 + s;  // pixel w + s  (covers w-1..w+1 via s)
        int sw = (wl + (wl >> 2)) & 3;
        afr[mf] = *reinterpret_cast<const bf16x8*>(&sX[((r * 130 + wl) * 4 + (lg ^ sw)) * 8]);
      }
      const uint4* wb = wp + (size_t)((c * 9 + rs) * NFRAG) * 64 + lane;
#pragma unroll
      for (int nf = 0; nf < NFRAG; ++nf) {
        uint4 bw = wb[nf * 64];
        bf16x8 bfr = __builtin_bit_cast(bf16x8, bw);
#pragma unroll
        for (int mf = 0; mf < 2; ++mf)
          acc[mf][nf] = __builtin_amdgcn_mfma_f32_16x16x32_bf16(afr[mf], bfr, acc[mf][nf], 0, 0, 0);
      }
    }
  }

  if (!PLANAR) {
    // NHWC bf16 out: D row=(lg*4+j) -> pixel, col=l15 -> co (m89-verified C/D map)
    ushort* out = (ushort*)outv;
#pragma unroll
    for (int nf = 0; nf < NFRAG; ++nf) {
      float bs = bias[nf * 16 + l15];
#pragma unroll
      for (int mf = 0; mf < 2; ++mf)
#pragma unroll
        for (int j = 0; j < 4; ++j) {
          int m = m0 + mf * 16 + lg * 4 + j;
          float v = acc[mf][nf][j] + bs;
          if (RELU) v = fmaxf(v, 0.f);
          out[((long)bid * 128 + m) * COUT + nf * 16 + l15] = f2bf_bits(v);
        }
    }
  } else {
    // conv4: [B,2,H,W] fp32 planar, only co<2 valid
    float* out = (float*)outv;
    if (l15 < 2) {
      float bs = bias[l15];
#pragma unroll
      for (int mf = 0; mf < 2; ++mf)
#pragma unroll
        for (int j = 0; j < 4; ++j) {
          int m = m0 + mf * 16 + lg * 4 + j;
          out[((long)(b * 2 + l15) * 128 + h) * 128 + m] = acc[mf][0][j] + bs;
        }
    }
  }
}

extern "C" void kernel_launch(void* const* d_in, const int* in_sizes, int n_in,
                              void* d_out, int out_size, void* d_ws, size_t ws_size,
                              hipStream_t stream) {
  (void)in_sizes; (void)n_in; (void)out_size; (void)ws_size;
  const float* f1 = (const float*)d_in[0];
  const float* f2 = (const float*)d_in[1];
  const float* w1 = (const float*)d_in[2];
  const float* b1 = (const float*)d_in[3];
  const float* w2 = (const float*)d_in[4];
  const float* b2 = (const float*)d_in[5];
  const float* w3 = (const float*)d_in[6];
  const float* b3 = (const float*)d_in[7];
  const float* w4 = (const float*)d_in[8];
  const float* b4 = (const float*)d_in[9];

  char* ws = (char*)d_ws;
  size_t off = 0;
  ushort* x0 = (ushort*)(ws + off); off += (size_t)262144 * 160 * 2;  // 83.9 MB
  ushort* x1 = (ushort*)(ws + off); off += (size_t)262144 * 128 * 2;  // 67.1 MB
  ushort* x2 = (ushort*)(ws + off); off += (size_t)262144 * 64 * 2;   // 33.6 MB
  uint4* wp1 = (uint4*)(ws + off); off += (size_t)5 * 9 * 8 * 64 * 16;
  uint4* wp2 = (uint4*)(ws + off); off += (size_t)4 * 9 * 4 * 64 * 16;
  uint4* wp3 = (uint4*)(ws + off); off += (size_t)2 * 9 * 2 * 64 * 16;
  uint4* wp4 = (uint4*)(ws + off); off += (size_t)1 * 9 * 1 * 64 * 16;
  ushort* x3 = x0;  // alias: x0 fully consumed by conv1 before conv3 writes

  prep_w_kernel<<<90, 256, 0, stream>>>(w1, wp1, 145, 128, 5, 8);
  prep_w_kernel<<<36, 256, 0, stream>>>(w2, wp2, 128, 64, 4, 4);
  prep_w_kernel<<<9, 256, 0, stream>>>(w3, wp3, 64, 32, 2, 2);
  prep_w_kernel<<<3, 256, 0, stream>>>(w4, wp4, 32, 2, 1, 1);

  cost_volume_kernel<<<dim3(128, 16), 128, 0, stream>>>(f1, f2, x0);

  conv_mfma_kernel<160, 128, true, false><<<2048, 256, 0, stream>>>(x0, wp1, b1, x1);
  conv_mfma_kernel<128, 64, true, false><<<2048, 256, 0, stream>>>(x1, wp2, b2, x2);
  conv_mfma_kernel<64, 32, true, false><<<2048, 256, 0, stream>>>(x2, wp3, b3, x3);
  conv_mfma_kernel<32, 16, false, true><<<2048, 256, 0, stream>>>(x3, wp4, b4, d_out);
}

// Round 3
// 1113.842 us; speedup vs baseline: 3.6325x; 1.2882x over previous
//
#include <hip/hip_runtime.h>

// B=16, H=W=128. NHWC bf16 activations: x0 160ch (64 f1 + 81 cv + 15 zero),
// x1 128ch, x2 64ch, x3 32ch. Output [B,2,H,W] fp32 planar.

typedef __bf16 bf16x8 __attribute__((ext_vector_type(8)));
typedef float f32x4 __attribute__((ext_vector_type(4)));

__device__ __forceinline__ unsigned short f2bf_bits(float f) {
  unsigned int u = __float_as_uint(f);
  unsigned int r = (u + 0x7FFFu + ((u >> 16) & 1u)) >> 16;  // RNE
  return (unsigned short)r;
}

// ---------------- weight prepack: OIHW fp32 -> B-fragment lane order bf16 ----
// wp[(c*9+rs)*NFRAG + nf][lane] = uint4 of 8 bf16: W[co=nf*16+(lane&15)][ci=c*32+8*(lane>>4)+e][rs]
__global__ void prep_w_kernel(const float* __restrict__ w, uint4* __restrict__ wp,
                              int CIN, int COUT, int CHUNKS, int NFRAG) {
  int idx = blockIdx.x * 256 + threadIdx.x;
  int total = CHUNKS * 9 * NFRAG * 64;
  if (idx >= total) return;
  int lane = idx & 63;
  int fi = idx >> 6;
  int nf = fi % NFRAG;
  int t = fi / NFRAG;
  int rs = t % 9;
  int c = t / 9;
  int co = nf * 16 + (lane & 15);
  int cib = c * 32 + (lane >> 4) * 8;
  union { uint4 q; ushort s[8]; } pk;
#pragma unroll
  for (int e = 0; e < 8; ++e) {
    int ci = cib + e;
    float v = (ci < CIN && co < COUT) ? w[(co * CIN + ci) * 9 + rs] : 0.f;
    pk.s[e] = f2bf_bits(v);
  }
  wp[idx] = pk.q;
}

// ---------------- cost volume + f1 pack -> x0 NHWC (160 ch) ----------------
// Block = one (b,h) output row; 256 thr = 4 waves. Thread: pixel pair (2p,2p+1),
// wave g owns ii subset {0,1}/{2,3}/{4,5}/{6,7,8}. Even/odd-split LDS: conflict-free.
__global__ __launch_bounds__(256)
void cost_volume_kernel(const float* __restrict__ f1,
                        const float* __restrict__ f2,
                        ushort* __restrict__ x0) {
  const int h = blockIdx.x;
  const int b = blockIdx.y;
  const int tid = threadIdx.x;
  const int p = tid & 63;      // pixel pair index: w0=2p, w1=2p+1
  const int g = tid >> 6;      // wave id
  const int iibase = (g < 3) ? 2 * g : 6;
  const int nv = (g < 3) ? 2 : 3;

  // sf2e[ci][a][m] = f2 col (2m-4) of row h+a-4 ; sf2o: col (2m-3). k=col+4 in [0,136)
  __shared__ float sf2e[4][9][69];
  __shared__ float sf2o[4][9][69];
  __shared__ float sf1e[4][64];
  __shared__ float sf1o[4][64];

  float acc[3][2][9];
#pragma unroll
  for (int s = 0; s < 3; ++s)
#pragma unroll
    for (int q = 0; q < 2; ++q)
#pragma unroll
      for (int jj = 0; jj < 9; ++jj) acc[s][q][jj] = 0.f;

  const long pix0 = (long)(b * 128 + h) * 128 + 2 * p;
  const long base0 = pix0 * 160;
  const long base1 = base0 + 160;

  for (int c0 = 0; c0 < 64; c0 += 4) {
    __syncthreads();
    // stage f2: 4 ci x 9 rows x 136 cols (zero OOB), split even/odd col
    for (int e = tid; e < 4 * 9 * 136; e += 256) {
      int ci = e / 1224;
      int rem = e - ci * 1224;
      int a = rem / 136;
      int k = rem - a * 136;
      int hh = h + a - 4;
      int gw = k - 4;
      float v = 0.f;
      if ((unsigned)hh < 128u && (unsigned)gw < 128u)
        v = f2[((b * 64 + c0 + ci) * 128 + hh) * 128 + gw];
      if (k & 1) sf2o[ci][a][k >> 1] = v; else sf2e[ci][a][k >> 1] = v;
    }
    // stage f1 row
    for (int e = tid; e < 4 * 128; e += 256) {
      int ci = e >> 7, ww = e & 127;
      float v = f1[((b * 64 + c0 + ci) * 128 + h) * 128 + ww];
      if (ww & 1) sf1o[ci][ww >> 1] = v; else sf1e[ci][ww >> 1] = v;
    }
    __syncthreads();

    // wave 0 packs f1 -> x0 ch c0..c0+3 (NHWC bf16) for both pixels
    if (g == 0) {
      union { uint2 q; ushort s[4]; } pk0, pk1;
#pragma unroll
      for (int ci = 0; ci < 4; ++ci) {
        pk0.s[ci] = f2bf_bits(sf1e[ci][p]);
        pk1.s[ci] = f2bf_bits(sf1o[ci][p]);
      }
      *reinterpret_cast<uint2*>(&x0[base0 + c0]) = pk0.q;
      *reinterpret_cast<uint2*>(&x0[base1 + c0]) = pk1.q;
    }

#pragma unroll
    for (int ci = 0; ci < 4; ++ci) {
      float f10 = sf1e[ci][p];
      float f11 = sf1o[ci][p];
#pragma unroll
      for (int s = 0; s < 3; ++s) {
        if (s < nv) {
          int row = 8 - (iibase + s);
          float ev[5], ov[5];
#pragma unroll
          for (int t = 0; t < 5; ++t) {
            ev[t] = sf2e[ci][row][p + t];
            ov[t] = sf2o[ci][row][p + t];
          }
#pragma unroll
          for (int jj = 0; jj < 9; ++jj) {
            int t0 = 8 - jj;  // col for pixel w0
            int t1 = 9 - jj;  // col for pixel w1
            float v0 = (t0 & 1) ? ov[(t0 - 1) >> 1] : ev[t0 >> 1];
            float v1 = (t1 & 1) ? ov[(t1 - 1) >> 1] : ev[t1 >> 1];
            acc[s][0][jj] += f10 * v0;
            acc[s][1][jj] += f11 * v1;
          }
        }
      }
    }
  }

  // write cv channels + zero pad
  const float inv = 1.0f / 64.0f;
#pragma unroll
  for (int s = 0; s < 3; ++s) {
    if (s < nv) {
      int ch = 64 + (iibase + s) * 9;
#pragma unroll
      for (int jj = 0; jj < 9; ++jj) {
        x0[base0 + ch + jj] = f2bf_bits(acc[s][0][jj] * inv);
        x0[base1 + ch + jj] = f2bf_bits(acc[s][1][jj] * inv);
      }
    }
  }
  if (g == 1) {  // zero pad ch 145..159
#pragma unroll
    for (int ch = 145; ch < 160; ++ch) {
      x0[base0 + ch] = 0;
      x0[base1 + ch] = 0;
    }
  }
}

// ---------------- implicit-GEMM 3x3 conv via bf16 MFMA ----------------
template <int CPAD, int COUT, bool RELU, bool PLANAR>
__global__ __launch_bounds__(256)
void conv_mfma_kernel(const ushort* __restrict__ xin, const uint4* __restrict__ wp,
                      const float* __restrict__ bias, void* __restrict__ outv) {
  constexpr int CHUNKS = CPAD / 32;
  constexpr int NFRAG = COUT / 16;

  __shared__ ushort sX[3 * 130 * 32];  // 24960 B

  const int bid = blockIdx.x;    // = b*128 + h
  const int h = bid & 127;
  const int b = bid >> 7;
  const int tid = threadIdx.x;
  const int lane = tid & 63;
  const int wid = tid >> 6;
  const int m0 = wid * 32;
  const int l15 = lane & 15;
  const int lg = lane >> 4;

  f32x4 acc[2][NFRAG];
#pragma unroll
  for (int mf = 0; mf < 2; ++mf)
#pragma unroll
    for (int nf = 0; nf < NFRAG; ++nf) acc[mf][nf] = {0.f, 0.f, 0.f, 0.f};

  for (int c = 0; c < CHUNKS; ++c) {
    const int c0 = c * 32;
    __syncthreads();
    for (int e = tid; e < 3 * 130 * 4; e += 256) {
      int row = e / 520;
      int rem = e - row * 520;
      int wl = rem >> 2;
      int g = rem & 3;
      int gh = h + row - 1;
      int gw = wl - 1;
      uint4 v = make_uint4(0u, 0u, 0u, 0u);
      if ((unsigned)gh < 128u && (unsigned)gw < 128u)
        v = *reinterpret_cast<const uint4*>(
            &xin[((long)(b * 128 + gh) * 128 + gw) * CPAD + c0 + g * 8]);
      int sw = (wl + (wl >> 2)) & 3;
      *reinterpret_cast<uint4*>(&sX[((row * 130 + wl) * 4 + (g ^ sw)) * 8]) = v;
    }
    __syncthreads();

#pragma unroll
    for (int rs = 0; rs < 9; ++rs) {
      const int r = rs / 3, s = rs % 3;
      bf16x8 afr[2];
#pragma unroll
      for (int mf = 0; mf < 2; ++mf) {
        int wl = m0 + mf * 16 + l15 + s;
        int sw = (wl + (wl >> 2)) & 3;
        afr[mf] = *reinterpret_cast<const bf16x8*>(&sX[((r * 130 + wl) * 4 + (lg ^ sw)) * 8]);
      }
      const uint4* wb = wp + (size_t)((c * 9 + rs) * NFRAG) * 64 + lane;
#pragma unroll
      for (int nf = 0; nf < NFRAG; ++nf) {
        uint4 bw = wb[nf * 64];
        bf16x8 bfr = __builtin_bit_cast(bf16x8, bw);
#pragma unroll
        for (int mf = 0; mf < 2; ++mf)
          acc[mf][nf] = __builtin_amdgcn_mfma_f32_16x16x32_bf16(afr[mf], bfr, acc[mf][nf], 0, 0, 0);
      }
    }
  }

  if (!PLANAR) {
    ushort* out = (ushort*)outv;
#pragma unroll
    for (int nf = 0; nf < NFRAG; ++nf) {
      float bs = bias[nf * 16 + l15];
#pragma unroll
      for (int mf = 0; mf < 2; ++mf)
#pragma unroll
        for (int j = 0; j < 4; ++j) {
          int m = m0 + mf * 16 + lg * 4 + j;
          float v = acc[mf][nf][j] + bs;
          if (RELU) v = fmaxf(v, 0.f);
          out[((long)bid * 128 + m) * COUT + nf * 16 + l15] = f2bf_bits(v);
        }
    }
  } else {
    float* out = (float*)outv;
    if (l15 < 2) {
      float bs = bias[l15];
#pragma unroll
      for (int mf = 0; mf < 2; ++mf)
#pragma unroll
        for (int j = 0; j < 4; ++j) {
          int m = m0 + mf * 16 + lg * 4 + j;
          out[((long)(b * 2 + l15) * 128 + h) * 128 + m] = acc[mf][0][j] + bs;
        }
    }
  }
}

extern "C" void kernel_launch(void* const* d_in, const int* in_sizes, int n_in,
                              void* d_out, int out_size, void* d_ws, size_t ws_size,
                              hipStream_t stream) {
  (void)in_sizes; (void)n_in; (void)out_size; (void)ws_size;
  const float* f1 = (const float*)d_in[0];
  const float* f2 = (const float*)d_in[1];
  const float* w1 = (const float*)d_in[2];
  const float* b1 = (const float*)d_in[3];
  const float* w2 = (const float*)d_in[4];
  const float* b2 = (const float*)d_in[5];
  const float* w3 = (const float*)d_in[6];
  const float* b3 = (const float*)d_in[7];
  const float* w4 = (const float*)d_in[8];
  const float* b4 = (const float*)d_in[9];

  char* ws = (char*)d_ws;
  size_t off = 0;
  ushort* x0 = (ushort*)(ws + off); off += (size_t)262144 * 160 * 2;  // 83.9 MB
  ushort* x1 = (ushort*)(ws + off); off += (size_t)262144 * 128 * 2;  // 67.1 MB
  ushort* x2 = (ushort*)(ws + off); off += (size_t)262144 * 64 * 2;   // 33.6 MB
  uint4* wp1 = (uint4*)(ws + off); off += (size_t)5 * 9 * 8 * 64 * 16;
  uint4* wp2 = (uint4*)(ws + off); off += (size_t)4 * 9 * 4 * 64 * 16;
  uint4* wp3 = (uint4*)(ws + off); off += (size_t)2 * 9 * 2 * 64 * 16;
  uint4* wp4 = (uint4*)(ws + off); off += (size_t)1 * 9 * 1 * 64 * 16;
  ushort* x3 = x0;  // alias: x0 fully consumed by conv1 before conv3 writes

  prep_w_kernel<<<90, 256, 0, stream>>>(w1, wp1, 145, 128, 5, 8);
  prep_w_kernel<<<36, 256, 0, stream>>>(w2, wp2, 128, 64, 4, 4);
  prep_w_kernel<<<9, 256, 0, stream>>>(w3, wp3, 64, 32, 2, 2);
  prep_w_kernel<<<3, 256, 0, stream>>>(w4, wp4, 32, 2, 1, 1);

  cost_volume_kernel<<<dim3(128, 16), 256, 0, stream>>>(f1, f2, x0);

  conv_mfma_kernel<160, 128, true, false><<<2048, 256, 0, stream>>>(x0, wp1, b1, x1);
  conv_mfma_kernel<128, 64, true, false><<<2048, 256, 0, stream>>>(x1, wp2, b2, x2);
  conv_mfma_kernel<64, 32, true, false><<<2048, 256, 0, stream>>>(x2, wp3, b3, x3);
  conv_mfma_kernel<32, 16, false, true><<<2048, 256, 0, stream>>>(x3, wp4, b4, d_out);
}

// Round 4
// 952.680 us; speedup vs baseline: 4.2470x; 1.1692x over previous
//
#include <hip/hip_runtime.h>

// B=16, H=W=128. Compact NHWC bf16: xf1 64ch, xcv 96ch (81 cv + 15 zero),
// x1 128ch, x2 64ch, x3 32ch. Output [B,2,H,W] fp32 planar.

typedef __bf16 bf16x8 __attribute__((ext_vector_type(8)));
typedef float f32x4 __attribute__((ext_vector_type(4)));

__device__ __forceinline__ unsigned short f2bf_bits(float f) {
  unsigned int u = __float_as_uint(f);
  unsigned int r = (u + 0x7FFFu + ((u >> 16) & 1u)) >> 16;  // RNE
  return (unsigned short)r;
}

// ---------------- weight prepack: OIHW fp32 -> B-fragment lane order bf16 ----
// wp[(c*9+rs)*NFRAG + nf][lane] = uint4 of 8 bf16: W[co=nf*16+(lane&15)][ci=c*32+8*(lane>>4)+e][rs]
__global__ void prep_w_kernel(const float* __restrict__ w, uint4* __restrict__ wp,
                              int CIN, int COUT, int CHUNKS, int NFRAG) {
  int idx = blockIdx.x * 256 + threadIdx.x;
  int total = CHUNKS * 9 * NFRAG * 64;
  if (idx >= total) return;
  int lane = idx & 63;
  int fi = idx >> 6;
  int nf = fi % NFRAG;
  int t = fi / NFRAG;
  int rs = t % 9;
  int c = t / 9;
  int co = nf * 16 + (lane & 15);
  int cib = c * 32 + (lane >> 4) * 8;
  union { uint4 q; ushort s[8]; } pk;
#pragma unroll
  for (int e = 0; e < 8; ++e) {
    int ci = cib + e;
    float v = (ci < CIN && co < COUT) ? w[(co * CIN + ci) * 9 + rs] : 0.f;
    pk.s[e] = f2bf_bits(v);
  }
  wp[idx] = pk.q;
}

// ---------------- f1 pack: NCHW fp32 -> compact NHWC bf16 (64 ch) -----------
__global__ __launch_bounds__(256) void pack_f1_kernel(const float* __restrict__ f1,
                                                      ushort* __restrict__ xf1) {
  __shared__ float tile[64][132];
  const int bid = blockIdx.x;
  const int h = bid & 127, b = bid >> 7;
  const int tid = threadIdx.x;
  for (int e = tid; e < 64 * 128; e += 256) {
    int c = e >> 7, w = e & 127;
    tile[c][w] = f1[((b * 64 + c) * 128 + h) * 128 + w];
  }
  __syncthreads();
  const int px = tid >> 1, cgb = (tid & 1) * 4;
  const long base = ((long)(b * 128 + h) * 128 + px) * 64;
#pragma unroll
  for (int e = 0; e < 4; ++e) {
    int c0 = (cgb + e) * 8;
    union { uint4 q; ushort s[8]; } pk;
#pragma unroll
    for (int k = 0; k < 8; ++k) pk.s[k] = f2bf_bits(tile[c0 + k][px]);
    *reinterpret_cast<uint4*>(&xf1[base + c0]) = pk.q;
  }
}

// ---------------- cost volume -> xcv compact NHWC (96 ch) -------------------
// Block = one (b,h) row; 256 thr = 4 waves. Thread: pixel pair (2p,2p+1),
// wave g owns ii subset {0,1}/{2,3}/{4,5}/{6,7,8}. Coalesced output via LDS staging.
__global__ __launch_bounds__(256)
void cost_volume_kernel(const float* __restrict__ f1,
                        const float* __restrict__ f2,
                        ushort* __restrict__ xcv) {
  // XCD-aware remap: xcd j gets b={2j,2j+1}, h contiguous
  const int bx = blockIdx.x;
  const int s0 = bx >> 3;
  const int b = 2 * (bx & 7) + (s0 >> 7);
  const int h = s0 & 127;
  const int tid = threadIdx.x;
  const int p = tid & 63;      // pixel pair: w0=2p, w1=2p+1
  const int g = tid >> 6;      // wave id
  const int iibase = (g < 3) ? 2 * g : 6;
  const int nv = (g < 3) ? 2 : 3;

  __shared__ char arena[24576];
  float* sf2e = (float*)arena;          // [4][9][69]
  float* sf2o = sf2e + 2484;            // [4][9][69]
  float* sf1e = sf2o + 2484;            // [4][64]
  float* sf1o = sf1e + 256;             // [4][64]
  uint* sOut = (uint*)arena;            // [96][64] overlay (used after compute)

  float acc[3][2][9];
#pragma unroll
  for (int s = 0; s < 3; ++s)
#pragma unroll
    for (int q = 0; q < 2; ++q)
#pragma unroll
      for (int jj = 0; jj < 9; ++jj) acc[s][q][jj] = 0.f;

  for (int c0 = 0; c0 < 64; c0 += 4) {
    __syncthreads();
    for (int e = tid; e < 4 * 9 * 136; e += 256) {
      int ci = e / 1224;
      int rem = e - ci * 1224;
      int a = rem / 136;
      int k = rem - a * 136;
      int hh = h + a - 4;
      int gw = k - 4;
      float v = 0.f;
      if ((unsigned)hh < 128u && (unsigned)gw < 128u)
        v = f2[((b * 64 + c0 + ci) * 128 + hh) * 128 + gw];
      if (k & 1) sf2o[(ci * 9 + a) * 69 + (k >> 1)] = v;
      else       sf2e[(ci * 9 + a) * 69 + (k >> 1)] = v;
    }
    for (int e = tid; e < 4 * 128; e += 256) {
      int ci = e >> 7, ww = e & 127;
      float v = f1[((b * 64 + c0 + ci) * 128 + h) * 128 + ww];
      if (ww & 1) sf1o[ci * 64 + (ww >> 1)] = v;
      else        sf1e[ci * 64 + (ww >> 1)] = v;
    }
    __syncthreads();

#pragma unroll
    for (int ci = 0; ci < 4; ++ci) {
      float f10 = sf1e[ci * 64 + p];
      float f11 = sf1o[ci * 64 + p];
#pragma unroll
      for (int s = 0; s < 3; ++s) {
        if (s < nv) {
          int row = 8 - (iibase + s);
          float ev[5], ov[5];
#pragma unroll
          for (int t = 0; t < 5; ++t) {
            ev[t] = sf2e[(ci * 9 + row) * 69 + p + t];
            ov[t] = sf2o[(ci * 9 + row) * 69 + p + t];
          }
#pragma unroll
          for (int jj = 0; jj < 9; ++jj) {
            int t0 = 8 - jj;
            int t1 = 9 - jj;
            float v0 = (t0 & 1) ? ov[(t0 - 1) >> 1] : ev[t0 >> 1];
            float v1 = (t1 & 1) ? ov[(t1 - 1) >> 1] : ev[t1 >> 1];
            acc[s][0][jj] += f10 * v0;
            acc[s][1][jj] += f11 * v1;
          }
        }
      }
    }
  }

  __syncthreads();  // compute done; safe to overlay sOut onto sf2/sf1

  const float inv = 1.0f / 64.0f;
#pragma unroll
  for (int s = 0; s < 3; ++s) {
    if (s < nv) {
      int rbase = (iibase + s) * 9;
#pragma unroll
      for (int jj = 0; jj < 9; ++jj) {
        uint lo = f2bf_bits(acc[s][0][jj] * inv);
        uint hi = f2bf_bits(acc[s][1][jj] * inv);
        sOut[(rbase + jj) * 64 + p] = lo | (hi << 16);
      }
    }
  }
  for (int e = tid; e < 15 * 64; e += 256) sOut[81 * 64 + e] = 0u;
  __syncthreads();

  // coalesced store: thread -> (pixel, ch-half); 6 x uint4 = 96 B contiguous
  {
    const int px = tid & 127, halfc = tid >> 7;
    const long rowbase = (long)(b * 128 + h) * 128 * 96;
    ushort* dst = xcv + rowbase + (long)px * 96 + halfc * 48;
#pragma unroll
    for (int e = 0; e < 6; ++e) {
      union { uint4 q; ushort s[8]; } pk;
#pragma unroll
      for (int k = 0; k < 8; ++k) {
        int ch = halfc * 48 + e * 8 + k;
        uint wv = sOut[ch * 64 + (px >> 1)];
        pk.s[k] = (px & 1) ? (ushort)(wv >> 16) : (ushort)(wv & 0xffffu);
      }
      *reinterpret_cast<uint4*>(dst + e * 8) = pk.q;
    }
  }
}

// ---------------- implicit-GEMM 3x3 conv via bf16 MFMA ----------------
// Input channels: [0,CA) from xa (stride CA), [CA,CA+CB) from xb (stride CB).
template <int CA, int CB, int COUT, bool RELU, bool PLANAR>
__global__ __launch_bounds__(256)
void conv_mfma_kernel(const ushort* __restrict__ xa, const ushort* __restrict__ xb,
                      const uint4* __restrict__ wp, const float* __restrict__ bias,
                      void* __restrict__ outv) {
  constexpr int CHUNKS = (CA + CB) / 32;
  constexpr int NFRAG = COUT / 16;

  __shared__ ushort sX[3 * 130 * 32];  // 24960 B

  const int bx = blockIdx.x;
  const int s0x = bx >> 3;
  const int b = 2 * (bx & 7) + (s0x >> 7);
  const int h = s0x & 127;
  const int rowid = b * 128 + h;
  const int tid = threadIdx.x;
  const int lane = tid & 63;
  const int wid = tid >> 6;
  const int m0 = wid * 32;
  const int l15 = lane & 15;
  const int lg = lane >> 4;

  f32x4 acc[2][NFRAG];
#pragma unroll
  for (int mf = 0; mf < 2; ++mf)
#pragma unroll
    for (int nf = 0; nf < NFRAG; ++nf) acc[mf][nf] = {0.f, 0.f, 0.f, 0.f};

  for (int c = 0; c < CHUNKS; ++c) {
    const int c0 = c * 32;
    const ushort* src;
    int cst, coff;
    if (CB == 0 || c0 < CA) { src = xa; cst = CA; coff = c0; }
    else                    { src = xb; cst = CB; coff = c0 - CA; }
    __syncthreads();
    for (int e = tid; e < 3 * 130 * 4; e += 256) {
      int row = e / 520;
      int rem = e - row * 520;
      int wl = rem >> 2;
      int g = rem & 3;
      int gh = h + row - 1;
      int gw = wl - 1;
      uint4 v = make_uint4(0u, 0u, 0u, 0u);
      if ((unsigned)gh < 128u && (unsigned)gw < 128u)
        v = *reinterpret_cast<const uint4*>(
            &src[((long)(b * 128 + gh) * 128 + gw) * cst + coff + g * 8]);
      int sw = (wl + (wl >> 2)) & 3;
      *reinterpret_cast<uint4*>(&sX[((row * 130 + wl) * 4 + (g ^ sw)) * 8]) = v;
    }
    __syncthreads();

#pragma unroll
    for (int rs = 0; rs < 9; ++rs) {
      const int r = rs / 3, s = rs % 3;
      bf16x8 afr[2];
#pragma unroll
      for (int mf = 0; mf < 2; ++mf) {
        int wl = m0 + mf * 16 + l15 + s;
        int sw = (wl + (wl >> 2)) & 3;
        afr[mf] = *reinterpret_cast<const bf16x8*>(&sX[((r * 130 + wl) * 4 + (lg ^ sw)) * 8]);
      }
      const uint4* wb = wp + (size_t)((c * 9 + rs) * NFRAG) * 64 + lane;
#pragma unroll
      for (int nf = 0; nf < NFRAG; ++nf) {
        uint4 bw = wb[nf * 64];
        bf16x8 bfr = __builtin_bit_cast(bf16x8, bw);
#pragma unroll
        for (int mf = 0; mf < 2; ++mf)
          acc[mf][nf] = __builtin_amdgcn_mfma_f32_16x16x32_bf16(afr[mf], bfr, acc[mf][nf], 0, 0, 0);
      }
    }
  }

  if (!PLANAR) {
    ushort* out = (ushort*)outv;
#pragma unroll
    for (int nf = 0; nf < NFRAG; ++nf) {
      float bs = bias[nf * 16 + l15];
#pragma unroll
      for (int mf = 0; mf < 2; ++mf)
#pragma unroll
        for (int j = 0; j < 4; ++j) {
          int m = m0 + mf * 16 + lg * 4 + j;
          float v = acc[mf][nf][j] + bs;
          if (RELU) v = fmaxf(v, 0.f);
          out[((long)rowid * 128 + m) * COUT + nf * 16 + l15] = f2bf_bits(v);
        }
    }
  } else {
    float* out = (float*)outv;
    if (l15 < 2) {
      float bs = bias[l15];
#pragma unroll
      for (int mf = 0; mf < 2; ++mf)
#pragma unroll
        for (int j = 0; j < 4; ++j) {
          int m = m0 + mf * 16 + lg * 4 + j;
          out[((long)(b * 2 + l15) * 128 + h) * 128 + m] = acc[mf][0][j] + bs;
        }
    }
  }
}

extern "C" void kernel_launch(void* const* d_in, const int* in_sizes, int n_in,
                              void* d_out, int out_size, void* d_ws, size_t ws_size,
                              hipStream_t stream) {
  (void)in_sizes; (void)n_in; (void)out_size; (void)ws_size;
  const float* f1 = (const float*)d_in[0];
  const float* f2 = (const float*)d_in[1];
  const float* w1 = (const float*)d_in[2];
  const float* b1 = (const float*)d_in[3];
  const float* w2 = (const float*)d_in[4];
  const float* b2 = (const float*)d_in[5];
  const float* w3 = (const float*)d_in[6];
  const float* b3 = (const float*)d_in[7];
  const float* w4 = (const float*)d_in[8];
  const float* b4 = (const float*)d_in[9];

  char* ws = (char*)d_ws;
  size_t off = 0;
  ushort* xf1 = (ushort*)(ws + off); off += (size_t)262144 * 64 * 2;   // 33.5 MB
  ushort* xcv = (ushort*)(ws + off); off += (size_t)262144 * 96 * 2;   // 50.3 MB
  ushort* x1  = (ushort*)(ws + off); off += (size_t)262144 * 128 * 2;  // 67.1 MB
  ushort* x2  = (ushort*)(ws + off); off += (size_t)262144 * 64 * 2;   // 33.6 MB
  uint4* wp1 = (uint4*)(ws + off); off += (size_t)5 * 9 * 8 * 64 * 16;
  uint4* wp2 = (uint4*)(ws + off); off += (size_t)4 * 9 * 4 * 64 * 16;
  uint4* wp3 = (uint4*)(ws + off); off += (size_t)2 * 9 * 2 * 64 * 16;
  uint4* wp4 = (uint4*)(ws + off); off += (size_t)1 * 9 * 1 * 64 * 16;
  ushort* x3 = xf1;  // alias: xf1 fully consumed by conv1 before conv3 writes

  prep_w_kernel<<<90, 256, 0, stream>>>(w1, wp1, 145, 128, 5, 8);
  prep_w_kernel<<<36, 256, 0, stream>>>(w2, wp2, 128, 64, 4, 4);
  prep_w_kernel<<<9, 256, 0, stream>>>(w3, wp3, 64, 32, 2, 2);
  prep_w_kernel<<<3, 256, 0, stream>>>(w4, wp4, 32, 2, 1, 1);

  pack_f1_kernel<<<2048, 256, 0, stream>>>(f1, xf1);
  cost_volume_kernel<<<2048, 256, 0, stream>>>(f1, f2, xcv);

  conv_mfma_kernel<64, 96, 128, true, false><<<2048, 256, 0, stream>>>(xf1, xcv, wp1, b1, x1);
  conv_mfma_kernel<128, 0, 64, true, false><<<2048, 256, 0, stream>>>(x1, x1, wp2, b2, x2);
  conv_mfma_kernel<64, 0, 32, true, false><<<2048, 256, 0, stream>>>(x2, x2, wp3, b3, x3);
  conv_mfma_kernel<32, 0, 16, false, true><<<2048, 256, 0, stream>>>(x3, x3, wp4, b4, d_out);
}

// Round 6
// 513.277 us; speedup vs baseline: 7.8828x; 1.8561x over previous
//
#include <hip/hip_runtime.h>

// B=16, H=W=128. Compact NHWC bf16: xf1 64ch, xcv 96ch (81 cv + 15 zero),
// x1 128ch, x2 64ch, x3 32ch. Output [B,2,H,W] fp32 planar.

typedef __bf16 bf16x8 __attribute__((ext_vector_type(8)));
typedef float f32x4 __attribute__((ext_vector_type(4)));

__device__ __forceinline__ unsigned short f2bf_bits(float f) {
  unsigned int u = __float_as_uint(f);
  unsigned int r = (u + 0x7FFFu + ((u >> 16) & 1u)) >> 16;  // RNE
  return (unsigned short)r;
}

// ---------------- weight prepack: OIHW fp32 -> B-fragment lane order bf16 ----
__global__ void prep_w_kernel(const float* __restrict__ w, uint4* __restrict__ wp,
                              int CIN, int COUT, int CHUNKS, int NFRAG) {
  int idx = blockIdx.x * 256 + threadIdx.x;
  int total = CHUNKS * 9 * NFRAG * 64;
  if (idx >= total) return;
  int lane = idx & 63;
  int fi = idx >> 6;
  int nf = fi % NFRAG;
  int t = fi / NFRAG;
  int rs = t % 9;
  int c = t / 9;
  int co = nf * 16 + (lane & 15);
  int cib = c * 32 + (lane >> 4) * 8;
  union { uint4 q; ushort s[8]; } pk;
#pragma unroll
  for (int e = 0; e < 8; ++e) {
    int ci = cib + e;
    float v = (ci < CIN && co < COUT) ? w[(co * CIN + ci) * 9 + rs] : 0.f;
    pk.s[e] = f2bf_bits(v);
  }
  wp[idx] = pk.q;
}

// ---------------- f1 pack: NCHW fp32 -> compact NHWC bf16 (64 ch) -----------
__global__ __launch_bounds__(256) void pack_f1_kernel(const float* __restrict__ f1,
                                                      ushort* __restrict__ xf1) {
  __shared__ float tile[64][132];
  const int bid = blockIdx.x;
  const int h = bid & 127, b = bid >> 7;
  const int tid = threadIdx.x;
  for (int e = tid; e < 64 * 128; e += 256) {
    int c = e >> 7, w = e & 127;
    tile[c][w] = f1[((b * 64 + c) * 128 + h) * 128 + w];
  }
  __syncthreads();
  const int px = tid >> 1, cgb = (tid & 1) * 4;
  const long base = ((long)(b * 128 + h) * 128 + px) * 64;
#pragma unroll
  for (int e = 0; e < 4; ++e) {
    int c0 = (cgb + e) * 8;
    union { uint4 q; ushort s[8]; } pk;
#pragma unroll
    for (int k = 0; k < 8; ++k) pk.s[k] = f2bf_bits(tile[c0 + k][px]);
    *reinterpret_cast<uint4*>(&xf1[base + c0]) = pk.q;
  }
}

// ---------------- cost volume -> xcv compact NHWC (96 ch) -------------------
// Block = 2 output rows (h0, h0+1); 256 thr = 4 waves. Thread: pixel QUAD
// (4q..4q+3) in row h0+rho. Wave g: full ii {2g,2g+1} + jj-subset of ii=8.
// Reg-staged double-buffered LDS; vectorized float4 LDS reads.
__global__ __launch_bounds__(256)
void cost_volume_kernel(const float* __restrict__ f1,
                        const float* __restrict__ f2,
                        ushort* __restrict__ xcv) {
  const int bx = blockIdx.x;           // 1024 blocks
  const int idx = bx >> 3;
  const int b = 2 * (bx & 7) + (idx >> 6);
  const int h0 = (idx & 63) * 2;
  const int tid = threadIdx.x;
  const int q = tid & 31;              // pixel quad: px 4q..4q+3
  const int rho = (tid >> 5) & 1;      // output row h0+rho
  const int g = tid >> 6;              // wave id

  // double buffer: per buf 3232 floats = f2[2ci][10a][136k] (2720) + f1[2ci][2r][128] (512)
  // overlay for output staging: [2][96][130] ushort (49920 B)
  __shared__ float arena[12480];

  float accF[2][9][4];                 // full ii = 2g+s
  float accP[3][4];                    // partial ii=8, up to 3 jj
#pragma unroll
  for (int s = 0; s < 2; ++s)
#pragma unroll
    for (int jj = 0; jj < 9; ++jj)
#pragma unroll
      for (int e = 0; e < 4; ++e) accF[s][jj][e] = 0.f;
#pragma unroll
  for (int t = 0; t < 3; ++t)
#pragma unroll
    for (int e = 0; e < 4; ++e) accP[t][e] = 0.f;

  float st[13];

  auto stage = [&](int c) {
    const int cc = c * 2;
#pragma unroll
    for (int i = 0; i < 13; ++i) {
      int e = tid + i * 256;
      float v = 0.f;
      if (e < 2720) {
        int ci = e / 1360;
        int rem = e - ci * 1360;
        int a = rem / 136;
        int k = rem - a * 136;
        int gh = h0 - 4 + a, gw = k - 4;
        if ((unsigned)gh < 128u && (unsigned)gw < 128u)
          v = f2[((b * 64 + cc + ci) * 128 + gh) * 128 + gw];
      } else if (e < 3232) {
        int e2 = e - 2720;
        int ci = e2 >> 8, rr = (e2 >> 7) & 1, ww = e2 & 127;
        v = f1[((b * 64 + cc + ci) * 128 + h0 + rr) * 128 + ww];
      }
      st[i] = v;
    }
  };
  auto commit = [&](int bi) {
    float* bufp = arena + bi * 3232;
#pragma unroll
    for (int i = 0; i < 13; ++i) {
      int e = tid + i * 256;
      if (e < 3232) bufp[e] = st[i];
    }
  };

  stage(0);
  commit(0);

  for (int c = 0; c < 32; ++c) {
    __syncthreads();
    if (c < 31) stage(c + 1);
    const float* bufc = arena + (c & 1) * 3232;
#pragma unroll
    for (int ci = 0; ci < 2; ++ci) {
      const float* bp = bufc + ci * 1360;
      float4 f1q = *reinterpret_cast<const float4*>(bufc + 2720 + ci * 256 + rho * 128 + 4 * q);
      const float* f1e = &f1q.x;
#pragma unroll
      for (int s = 0; s < 2; ++s) {
        int a = rho + 8 - (2 * g + s);
        const float* rp = bp + a * 136 + 4 * q;
        float4 A = *reinterpret_cast<const float4*>(rp);
        float4 Bv = *reinterpret_cast<const float4*>(rp + 4);
        float4 Cv = *reinterpret_cast<const float4*>(rp + 8);
        float ev[12] = {A.x, A.y, A.z, A.w, Bv.x, Bv.y, Bv.z, Bv.w, Cv.x, Cv.y, Cv.z, Cv.w};
#pragma unroll
        for (int jj = 0; jj < 9; ++jj)
#pragma unroll
          for (int e = 0; e < 4; ++e)
            accF[s][jj][e] += f1e[e] * ev[8 - jj + e];
      }
      // partial ii=8 (f2 tile row a = rho)
      {
        const float* rp = bp + rho * 136 + 4 * q;
        if (g < 2) {
          float4 A = *reinterpret_cast<const float4*>(rp + 4);
          float4 Bv = *reinterpret_cast<const float4*>(rp + 8);
          float pv[8] = {A.x, A.y, A.z, A.w, Bv.x, Bv.y, Bv.z, Bv.w};  // t=4..11
          if (g == 0) {  // jj = 0,1,2
#pragma unroll
            for (int e = 0; e < 4; ++e) {
              accP[0][e] += f1e[e] * pv[4 + e];
              accP[1][e] += f1e[e] * pv[3 + e];
              accP[2][e] += f1e[e] * pv[2 + e];
            }
          } else {       // jj = 3,4
#pragma unroll
            for (int e = 0; e < 4; ++e) {
              accP[0][e] += f1e[e] * pv[1 + e];
              accP[1][e] += f1e[e] * pv[e];
            }
          }
        } else {
          float4 A = *reinterpret_cast<const float4*>(rp);
          float4 Bv = *reinterpret_cast<const float4*>(rp + 4);
          float pv[8] = {A.x, A.y, A.z, A.w, Bv.x, Bv.y, Bv.z, Bv.w};  // t=0..7
          if (g == 2) {  // jj = 5,6
#pragma unroll
            for (int e = 0; e < 4; ++e) {
              accP[0][e] += f1e[e] * pv[3 + e];
              accP[1][e] += f1e[e] * pv[2 + e];
            }
          } else {       // jj = 7,8
#pragma unroll
            for (int e = 0; e < 4; ++e) {
              accP[0][e] += f1e[e] * pv[1 + e];
              accP[1][e] += f1e[e] * pv[e];
            }
          }
        }
      }
    }
    if (c < 31) commit((c + 1) & 1);
  }

  __syncthreads();  // all compute done; overlay output staging
  ushort* sO = (ushort*)arena;  // [(r*96+ch)*130 + px]
  const float inv = 1.0f / 64.0f;
#pragma unroll
  for (int s = 0; s < 2; ++s) {
    int ch = (2 * g + s) * 9;
#pragma unroll
    for (int jj = 0; jj < 9; ++jj) {
      uint lo = (uint)f2bf_bits(accF[s][jj][0] * inv) | ((uint)f2bf_bits(accF[s][jj][1] * inv) << 16);
      uint hi = (uint)f2bf_bits(accF[s][jj][2] * inv) | ((uint)f2bf_bits(accF[s][jj][3] * inv) << 16);
      ushort* d = &sO[(rho * 96 + ch + jj) * 130 + 4 * q];
      *reinterpret_cast<uint*>(d) = lo;
      *reinterpret_cast<uint*>(d + 2) = hi;
    }
  }
  {
    const int npart = (g == 0) ? 3 : 2;
    const int chbase = 72 + ((g == 0) ? 0 : (g == 1) ? 3 : (g == 2) ? 5 : 7);
#pragma unroll
    for (int t = 0; t < 3; ++t) {
      if (t < npart) {
        uint lo = (uint)f2bf_bits(accP[t][0] * inv) | ((uint)f2bf_bits(accP[t][1] * inv) << 16);
        uint hi = (uint)f2bf_bits(accP[t][2] * inv) | ((uint)f2bf_bits(accP[t][3] * inv) << 16);
        ushort* d = &sO[(rho * 96 + chbase + t) * 130 + 4 * q];
        *reinterpret_cast<uint*>(d) = lo;
        *reinterpret_cast<uint*>(d + 2) = hi;
      }
    }
  }
  for (int e = tid; e < 1920; e += 256) {  // zero ch 81..95, both rows
    int r = e / 960;
    int rem = e - r * 960;
    int ch = 81 + (rem >> 6);
    int pxh = rem & 63;
    *reinterpret_cast<uint*>(&sO[(r * 96 + ch) * 130 + pxh * 2]) = 0u;
  }
  __syncthreads();

  // coalesced store: per row 1536 uint4 (128 px x 96 ch); 128 threads x 12 each
  {
    const int r = tid >> 7, u = tid & 127;
    uint4* dst = reinterpret_cast<uint4*>(xcv + ((long)(b * 128 + h0 + r) * 128) * 96);
#pragma unroll
    for (int j = 0; j < 12; ++j) {
      int t8 = 128 * j + u;           // 0..1535
      int px = t8 / 12;               // 0..127
      int ch0 = (t8 - px * 12) * 8;   // 0..88
      union { uint4 qq; ushort ss[8]; } pk;
#pragma unroll
      for (int k = 0; k < 8; ++k) pk.ss[k] = sO[(r * 96 + ch0 + k) * 130 + px];
      dst[t8] = pk.qq;
    }
  }
}

// ---------------- implicit-GEMM 3x3 conv via bf16 MFMA (2 rows, dbuf) -------
template <int CA, int CB, int COUT, bool RELU, bool PLANAR>
__global__ __launch_bounds__(256, 2)
void conv_mfma_kernel(const ushort* __restrict__ xa, const ushort* __restrict__ xb,
                      const uint4* __restrict__ wp, const float* __restrict__ bias,
                      void* __restrict__ outv) {
  constexpr int CHUNKS = (CA + CB) / 32;
  constexpr int NFRAG = COUT / 16;

  __shared__ ushort sX[2][4 * 130 * 32];  // 2 x 33280 B

  const int bx = blockIdx.x;              // 1024 blocks
  const int idx = bx >> 3;
  const int b = 2 * (bx & 7) + (idx >> 6);
  const int h0 = (idx & 63) * 2;
  const int tid = threadIdx.x;
  const int lane = tid & 63;
  const int wid = tid >> 6;
  const int m0 = wid * 32;
  const int l15 = lane & 15;
  const int lg = lane >> 4;

  f32x4 acc[4][NFRAG];
#pragma unroll
  for (int mf = 0; mf < 4; ++mf)
#pragma unroll
    for (int nf = 0; nf < NFRAG; ++nf) acc[mf][nf] = {0.f, 0.f, 0.f, 0.f};

  uint4 st[9];

  auto stage = [&](int c) {
    const int c0 = c * 32;
    const ushort* src;
    int cst, coff;
    if (CB == 0 || c0 < CA) { src = xa; cst = CA; coff = c0; }
    else                    { src = xb; cst = CB; coff = c0 - CA; }
#pragma unroll
    for (int i = 0; i < 9; ++i) {
      int e = tid + i * 256;
      if (e < 2080) {
        int row = e / 520;
        int rem = e - row * 520;
        int wl = rem >> 2;
        int gq = rem & 3;
        int gh = h0 - 1 + row, gw = wl - 1;
        uint4 v = make_uint4(0u, 0u, 0u, 0u);
        if ((unsigned)gh < 128u && (unsigned)gw < 128u)
          v = *reinterpret_cast<const uint4*>(
              &src[((long)(b * 128 + gh) * 128 + gw) * cst + coff + gq * 8]);
        st[i] = v;
      }
    }
  };
  auto commit = [&](int bi) {
#pragma unroll
    for (int i = 0; i < 9; ++i) {
      int e = tid + i * 256;
      if (e < 2080) {
        int row = e / 520;
        int rem = e - row * 520;
        int wl = rem >> 2;
        int gq = rem & 3;
        int sw = (wl + (wl >> 2)) & 3;
        *reinterpret_cast<uint4*>(&sX[bi][((row * 130 + wl) * 4 + (gq ^ sw)) * 8]) = st[i];
      }
    }
  };

  stage(0);
  commit(0);

  for (int c = 0; c < CHUNKS; ++c) {
    __syncthreads();
    if (c + 1 < CHUNKS) stage(c + 1);
    const int bi = c & 1;
#pragma unroll
    for (int rs = 0; rs < 9; ++rs) {
      const int r = rs / 3, s = rs % 3;
      bf16x8 afr[4];
#pragma unroll
      for (int mf = 0; mf < 4; ++mf) {
        int row = r + (mf >> 1);
        int wl = m0 + (mf & 1) * 16 + l15 + s;
        int sw = (wl + (wl >> 2)) & 3;
        afr[mf] = *reinterpret_cast<const bf16x8*>(&sX[bi][((row * 130 + wl) * 4 + (lg ^ sw)) * 8]);
      }
      const uint4* wb = wp + (size_t)((c * 9 + rs) * NFRAG) * 64 + lane;
#pragma unroll
      for (int nf = 0; nf < NFRAG; ++nf) {
        uint4 bw = wb[nf * 64];
        bf16x8 bfr = __builtin_bit_cast(bf16x8, bw);
#pragma unroll
        for (int mf = 0; mf < 4; ++mf)
          acc[mf][nf] = __builtin_amdgcn_mfma_f32_16x16x32_bf16(afr[mf], bfr, acc[mf][nf], 0, 0, 0);
      }
    }
    if (c + 1 < CHUNKS) commit((c + 1) & 1);
  }

  if (!PLANAR) {
    ushort* out = (ushort*)outv;
#pragma unroll
    for (int nf = 0; nf < NFRAG; ++nf) {
      float bs = bias[nf * 16 + l15];
#pragma unroll
      for (int mf = 0; mf < 4; ++mf) {
        int hh = h0 + (mf >> 1);
        int mb = m0 + (mf & 1) * 16 + lg * 4;
#pragma unroll
        for (int j = 0; j < 4; ++j) {
          float v = acc[mf][nf][j] + bs;
          if (RELU) v = fmaxf(v, 0.f);
          out[((long)(b * 128 + hh) * 128 + mb + j) * COUT + nf * 16 + l15] = f2bf_bits(v);
        }
      }
    }
  } else {
    float* out = (float*)outv;
    if (l15 < 2) {
      float bs = bias[l15];
#pragma unroll
      for (int mf = 0; mf < 4; ++mf) {
        int hh = h0 + (mf >> 1);
        int mb = m0 + (mf & 1) * 16 + lg * 4;
#pragma unroll
        for (int j = 0; j < 4; ++j)
          out[((long)(b * 2 + l15) * 128 + hh) * 128 + mb + j] = acc[mf][0][j] + bs;
      }
    }
  }
}

extern "C" void kernel_launch(void* const* d_in, const int* in_sizes, int n_in,
                              void* d_out, int out_size, void* d_ws, size_t ws_size,
                              hipStream_t stream) {
  (void)in_sizes; (void)n_in; (void)out_size; (void)ws_size;
  const float* f1 = (const float*)d_in[0];
  const float* f2 = (const float*)d_in[1];
  const float* w1 = (const float*)d_in[2];
  const float* b1 = (const float*)d_in[3];
  const float* w2 = (const float*)d_in[4];
  const float* b2 = (const float*)d_in[5];
  const float* w3 = (const float*)d_in[6];
  const float* b3 = (const float*)d_in[7];
  const float* w4 = (const float*)d_in[8];
  const float* b4 = (const float*)d_in[9];

  char* ws = (char*)d_ws;
  size_t off = 0;
  ushort* xf1 = (ushort*)(ws + off); off += (size_t)262144 * 64 * 2;
  ushort* xcv = (ushort*)(ws + off); off += (size_t)262144 * 96 * 2;
  ushort* x1  = (ushort*)(ws + off); off += (size_t)262144 * 128 * 2;
  ushort* x2  = (ushort*)(ws + off); off += (size_t)262144 * 64 * 2;
  uint4* wp1 = (uint4*)(ws + off); off += (size_t)5 * 9 * 8 * 64 * 16;
  uint4* wp2 = (uint4*)(ws + off); off += (size_t)4 * 9 * 4 * 64 * 16;
  uint4* wp3 = (uint4*)(ws + off); off += (size_t)2 * 9 * 2 * 64 * 16;
  uint4* wp4 = (uint4*)(ws + off); off += (size_t)1 * 9 * 1 * 64 * 16;
  ushort* x3 = xf1;  // alias: xf1 fully consumed by conv1 before conv3 writes

  prep_w_kernel<<<90, 256, 0, stream>>>(w1, wp1, 145, 128, 5, 8);
  prep_w_kernel<<<36, 256, 0, stream>>>(w2, wp2, 128, 64, 4, 4);
  prep_w_kernel<<<9, 256, 0, stream>>>(w3, wp3, 64, 32, 2, 2);
  prep_w_kernel<<<3, 256, 0, stream>>>(w4, wp4, 32, 2, 1, 1);

  pack_f1_kernel<<<2048, 256, 0, stream>>>(f1, xf1);
  cost_volume_kernel<<<1024, 256, 0, stream>>>(f1, f2, xcv);

  conv_mfma_kernel<64, 96, 128, true, false><<<1024, 256, 0, stream>>>(xf1, xcv, wp1, b1, x1);
  conv_mfma_kernel<128, 0, 64, true, false><<<1024, 256, 0, stream>>>(x1, x1, wp2, b2, x2);
  conv_mfma_kernel<64, 0, 32, true, false><<<1024, 256, 0, stream>>>(x2, x2, wp3, b3, x3);
  conv_mfma_kernel<32, 0, 16, false, true><<<1024, 256, 0, stream>>>(x3, x3, wp4, b4, d_out);
}